// Round 1
// baseline (89.070 us; speedup 1.0000x reference)
//
#include <hip/hip_runtime.h>

// Problem geometry (fixed by setup_inputs):
//   img: (1080, 1920, 3) fp32; x = img[3:-3] -> (1074, 1920, 3)
//   vertical median, window 5, symmetric padding along axis 0.
//
// R5 theory: kernel portion is latency-bound, not BW-bound.
//   - True HBM traffic is ~50 MB (25 in + 25 out); input fits in 256 MB L3,
//     so halo re-reads are cache-absorbed -> read amplification is ~free.
//   - RPB=8 gave only 810 blocks = 3.2 blocks/CU (12.6/32 waves/CU).
//     R4 already showed fewer blocks (RPB=16, 408) regress: latency hiding
//     dominates, halo savings don't.
//   - RPB=2: 1074 = 537*2 exactly -> 3222 blocks = 12.6 blocks/CU
//     (occupancy-saturated), no partial strip, no loop/break: straight-line
//     code with 6 independent loads issued up front, 2 medians, 2 stores.
#define N_ROWS 1074          // output rows
#define ROW_V4 1440          // float4 per row (1920*3/4)
#define RPB    2             // output rows per thread (exact: 537 strips)

__device__ __forceinline__ void cswap(float& a, float& b) {
    float lo = fminf(a, b);
    b = fmaxf(a, b);
    a = lo;
}

// Devillard opt_med5: 7 compare-exchanges, result in p2.
__device__ __forceinline__ float med5(float p0, float p1, float p2, float p3, float p4) {
    cswap(p0, p1); cswap(p3, p4); cswap(p0, p3);
    cswap(p1, p4); cswap(p1, p2); cswap(p2, p3);
    cswap(p1, p2);
    return p2;
}

__device__ __forceinline__ float4 med5v(const float4& a, const float4& b,
                                        const float4& c, const float4& d,
                                        const float4& e) {
    float4 r;
    r.x = med5(a.x, b.x, c.x, d.x, e.x);
    r.y = med5(a.y, b.y, c.y, d.y, e.y);
    r.z = med5(a.z, b.z, c.z, d.z, e.z);
    r.w = med5(a.w, b.w, c.w, d.w, e.w);
    return r;
}

__global__ __launch_bounds__(256)
void VerticalMedian_54262616818099_kernel(const float* __restrict__ img,
                                          float* __restrict__ out) {
    const int c4 = blockIdx.x * 256 + threadIdx.x;   // float4 column index
    if (c4 >= ROW_V4) return;
    const int i0 = blockIdx.y * RPB;                 // first output row of strip

    const float4* __restrict__ in4 = (const float4*)img + c4;
    float4* __restrict__ o4 = (float4*)out + c4;

    // Load one (reflected) window row; +3 crops img[3:-3].
    auto ld = [&](int j) -> float4 {
        j = (j < 0) ? (-1 - j) : j;                    // symmetric reflect top
        j = (j >= N_ROWS) ? (2 * N_ROWS - 1 - j) : j;  // symmetric reflect bottom
        return in4[(size_t)(j + 3) * ROW_V4];
    };

    // 6 independent loads, all issued before any use -> max MLP per wave.
    float4 w0 = ld(i0 - 2);
    float4 w1 = ld(i0 - 1);
    float4 w2 = ld(i0);
    float4 w3 = ld(i0 + 1);
    float4 w4 = ld(i0 + 2);
    float4 w5 = ld(i0 + 3);

    o4[(size_t)i0 * ROW_V4]       = med5v(w0, w1, w2, w3, w4);
    o4[(size_t)(i0 + 1) * ROW_V4] = med5v(w1, w2, w3, w4, w5);
}

extern "C" void kernel_launch(void* const* d_in, const int* in_sizes, int n_in,
                              void* d_out, int out_size, void* d_ws, size_t ws_size,
                              hipStream_t stream) {
    const float* img = (const float*)d_in[0];
    // d_in[1] = mask (unused by reference output), d_in[2] = vertical_size (fixed 5)
    float* out = (float*)d_out;

    dim3 block(256, 1, 1);
    dim3 grid((ROW_V4 + 255) / 256,                    // 6 column chunks
              N_ROWS / RPB, 1);                        // 537 row strips (exact)
    VerticalMedian_54262616818099_kernel<<<grid, block, 0, stream>>>(img, out);
}

// Round 2
// 83.461 us; speedup vs baseline: 1.0672x; 1.0672x over previous
//
#include <hip/hip_runtime.h>

// Problem geometry (fixed by setup_inputs):
//   img: (1080, 1920, 3) fp32; x = img[3:-3] -> (1074, 1920, 3)
//   vertical median, window 5, symmetric padding along axis 0.
//
// R6 theory: kernel-part (~38.5 µs at RPB=8) is bound by a SERIALIZED load
// chain, not occupancy count:
//   - R5 (RPB=2, 3x read amplification) regressed by +5.7 µs ≈ extra 38 MB
//     at 6 TB/s -> the poison fill dirties all of L3, so halo re-reads are
//     cold HBM reads, NOT cache-absorbed. Keep amplification low.
//   - The rolling-window loop's runtime `break` prevents hoisting loads:
//     after priming, each iteration issues ONE load and waits (~900 cyc cold
//     HBM) -> ~12 serial latencies/wave * 3.2 blocks/CU ≈ 38 µs.
//   - RPB=6: 1074 = 179*6 EXACT -> no tail, no break, straight-line kernel.
//     All 10 row-loads issued up front (MLP 10), then 6 medians, 6 stores.
//     Amplification 1.67x (42 MB reads), 1074 blocks = 4.2/CU.
#define N_ROWS 1074          // output rows
#define ROW_V4 1440          // float4 per row (1920*3/4)
#define RPB    6             // output rows per thread (exact: 179 strips)
#define NLD    (RPB + 4)     // window rows loaded per thread

__device__ __forceinline__ void cswap(float& a, float& b) {
    float lo = fminf(a, b);
    b = fmaxf(a, b);
    a = lo;
}

// Devillard opt_med5: 7 compare-exchanges, result in p2.
__device__ __forceinline__ float med5(float p0, float p1, float p2, float p3, float p4) {
    cswap(p0, p1); cswap(p3, p4); cswap(p0, p3);
    cswap(p1, p4); cswap(p1, p2); cswap(p2, p3);
    cswap(p1, p2);
    return p2;
}

__device__ __forceinline__ float4 med5v(const float4& a, const float4& b,
                                        const float4& c, const float4& d,
                                        const float4& e) {
    float4 r;
    r.x = med5(a.x, b.x, c.x, d.x, e.x);
    r.y = med5(a.y, b.y, c.y, d.y, e.y);
    r.z = med5(a.z, b.z, c.z, d.z, e.z);
    r.w = med5(a.w, b.w, c.w, d.w, e.w);
    return r;
}

__global__ __launch_bounds__(256)
void VerticalMedian_54262616818099_kernel(const float* __restrict__ img,
                                          float* __restrict__ out) {
    const int c4 = blockIdx.x * 256 + threadIdx.x;   // float4 column index
    if (c4 >= ROW_V4) return;
    const int i0 = blockIdx.y * RPB;                 // first output row of strip

    const float4* __restrict__ in4 = (const float4*)img + c4;
    float4* __restrict__ o4 = (float4*)out + c4;

    // Issue ALL window-row loads before any use -> full memory-level
    // parallelism per wave. Reflection handled branchlessly in the index.
    float4 w[NLD];
#pragma unroll
    for (int k = 0; k < NLD; ++k) {
        int j = i0 + k - 2;
        j = (j < 0) ? (-1 - j) : j;                    // symmetric reflect top
        j = (j >= N_ROWS) ? (2 * N_ROWS - 1 - j) : j;  // symmetric reflect bottom
        w[k] = in4[(size_t)(j + 3) * ROW_V4];          // +3 crops img[3:-3]
    }

#pragma unroll
    for (int r = 0; r < RPB; ++r) {
        o4[(size_t)(i0 + r) * ROW_V4] =
            med5v(w[r], w[r + 1], w[r + 2], w[r + 3], w[r + 4]);
    }
}

extern "C" void kernel_launch(void* const* d_in, const int* in_sizes, int n_in,
                              void* d_out, int out_size, void* d_ws, size_t ws_size,
                              hipStream_t stream) {
    const float* img = (const float*)d_in[0];
    // d_in[1] = mask (unused by reference output), d_in[2] = vertical_size (fixed 5)
    float* out = (float*)d_out;

    dim3 block(256, 1, 1);
    dim3 grid((ROW_V4 + 255) / 256,                    // 6 column chunks
              N_ROWS / RPB, 1);                        // 179 row strips (exact)
    VerticalMedian_54262616818099_kernel<<<grid, block, 0, stream>>>(img, out);
}